// Round 5
// baseline (263.333 us; speedup 1.0000x reference)
//
#include <hip/hip_runtime.h>
#include <hip/hip_bf16.h>
#include <math.h>

// Problem constants
#define T_LEN 2048
#define BSZ   2
#define EMB   1024
#define NH    16
#define HD    64
#define BHN   (BSZ*NH)      // 32
#define M1    (T_LEN*BSZ)   // 4096 rows of the projection GEMMs
#define SCAL  0.125f        // HD^-0.5
#define QSCALE (0.125f * 1.44269504088896f)   // SCAL * log2(e): softmax uses exp2

typedef __attribute__((ext_vector_type(8))) short bf16x8;   // 8 bf16 = 4 VGPRs
typedef __attribute__((ext_vector_type(4))) float f32x4;
typedef __attribute__((ext_vector_type(2))) unsigned int u32x2;

__device__ inline unsigned short f2bf(float x) {
    union { float f; unsigned u; } v; v.f = x;
    unsigned r = v.u + 0x7FFF + ((v.u >> 16) & 1);   // RNE
    return (unsigned short)(r >> 16);
}

// packed f32x2 -> bf16x2 (v_cvt_pk_bf16_f32 on gfx950 via hip_bf16.h)
__device__ inline unsigned pack2bf(float a, float b) {
    union { __hip_bfloat162 h; unsigned u; } v;
    v.h = __float22bfloat162_rn(make_float2(a, b));
    return v.u;
}

__device__ inline float fexp2(float x) {
#if __has_builtin(__builtin_amdgcn_exp2f)
    return __builtin_amdgcn_exp2f(x);
#else
    return exp2f(x);
#endif
}

// async global->LDS, 16B per lane (wave-uniform LDS base + lane*16)
__device__ inline void async16(const unsigned short* g, unsigned short* l) {
    __builtin_amdgcn_global_load_lds(
        (const __attribute__((address_space(1))) void*)g,
        (__attribute__((address_space(3))) void*)l, 16, 0, 0);
}

// light barrier: IR-level memory fence + raw s_barrier. No vmcnt(0) drain
// (counted vmcnt handles staging), no sched_barrier(0) order-pinning (m141).
__device__ inline void bar() {
    asm volatile("" ::: "memory");
    __builtin_amdgcn_s_barrier();
    asm volatile("" ::: "memory");
}

// XOR-swizzled LDS address, 8 chunks (16B) per row: slot = c ^ (r&7).
__device__ inline const unsigned short* swz(const unsigned short* base, int r, int c) {
    return base + (((r << 3) + (c ^ (r & 7))) << 3);
}
// 16 chunks per row variant (row stride 256B); XOR on low 3 bits only.
__device__ inline const unsigned short* swz16(const unsigned short* base, int r, int c) {
    return base + (((r << 4) + (c ^ (r & 7))) << 3);
}

// In-register redistribution of the S^T (K*Q^T) output layout into the PV
// B-operand layout. Pure lane permutation among {l16, l16+16, l16+32, l16+48}.
__device__ inline void xchg(unsigned e, unsigned o, unsigned& w_lo, unsigned& w_hi) {
#if __has_builtin(__builtin_amdgcn_permlane32_swap) && __has_builtin(__builtin_amdgcn_permlane16_swap)
    u32x2 x = __builtin_amdgcn_permlane32_swap(e, o, false, false);
    u32x2 y = __builtin_amdgcn_permlane16_swap(x[0], x[1], false, false);
    w_lo = y[0]; w_hi = y[1];
#else
    int lane = (int)(threadIdx.x & 63);
    int quad = lane >> 4, l16 = lane & 15;
    int srcA = ((quad & 1) * 2) * 16 + l16;
    int srcB = ((quad & 1) * 2 + 1) * 16 + l16;
    unsigned ea = (unsigned)__shfl((int)e, srcA, 64);
    unsigned oa = (unsigned)__shfl((int)o, srcA, 64);
    unsigned eb = (unsigned)__shfl((int)e, srcB, 64);
    unsigned ob = (unsigned)__shfl((int)o, srcB, 64);
    w_lo = (quad >> 1) ? oa : ea;
    w_hi = (quad >> 1) ? ob : eb;
#endif
}

// ---------------------------------------------------------------------------
// Kernel 0: fused fp32 -> bf16 convert of all three inputs.
// ---------------------------------------------------------------------------
__global__ __launch_bounds__(256) void cvt3_kernel(
    const float* __restrict__ s0, const float* __restrict__ s1,
    const float* __restrict__ s2, unsigned short* __restrict__ dst,
    int n0, int n1)
{
    int idx = blockIdx.x * 256 + threadIdx.x;
    const float* src; int o;
    if (idx < n0)           { src = s0; o = idx; }
    else if (idx < n0 + n1) { src = s1; o = idx - n0; }
    else                    { src = s2; o = idx - n0 - n1; }
    float4 a = reinterpret_cast<const float4*>(src)[(size_t)o * 2];
    float4 c = reinterpret_cast<const float4*>(src)[(size_t)o * 2 + 1];
    unsigned w[4] = { pack2bf(a.x, a.y), pack2bf(a.z, a.w),
                      pack2bf(c.x, c.y), pack2bf(c.z, c.w) };
    reinterpret_cast<uint4*>(dst)[idx] = *reinterpret_cast<uint4*>(w);
}

// ---------------------------------------------------------------------------
// Kernel 1: QKV projection, bf16 MFMA (m97 structure).
// Q16 is pre-scaled by SCAL*log2(e) so attention softmax can use raw exp2.
// ---------------------------------------------------------------------------
__global__ __launch_bounds__(256) void qkv_mfma_kernel(
    const unsigned short* __restrict__ A, const unsigned short* __restrict__ B,
    const float* __restrict__ bias,
    unsigned short* __restrict__ Q16, unsigned short* __restrict__ K16,
    unsigned short* __restrict__ Vt16)
{
    constexpr int BM = 128, BN = 128, BK = 32, K = 1024;
    __shared__ unsigned short As[BM * BK];   // contiguous, no pad (global_load_lds)
    __shared__ unsigned short Bs[BN * BK];
    const int tid = threadIdx.x;
    const int lane = tid & 63, wave = tid >> 6;
    const int quad = lane >> 4, l16 = lane & 15;
    const int wr = wave >> 1, wc = wave & 1;
    const int m0 = blockIdx.x * BM, n0 = blockIdx.y * BN;

    f32x4 zero4 = {0.f, 0.f, 0.f, 0.f};
    f32x4 acc[4][4];
    #pragma unroll
    for (int i = 0; i < 4; ++i)
        #pragma unroll
        for (int j = 0; j < 4; ++j) acc[i][j] = zero4;

    for (int k0 = 0; k0 < K; k0 += BK) {
        __syncthreads();
        #pragma unroll
        for (int t = 0; t < 2; ++t) {
            int c = t * 256 + tid;           // 16B chunk id, 0..511
            int m = c >> 2, kb = c & 3;
            async16(&A[(size_t)(m0 + m) * K + k0 + kb * 8], &As[c * 8]);
            async16(&B[(size_t)(n0 + m) * K + k0 + kb * 8], &Bs[c * 8]);
        }
        __syncthreads();
        bf16x8 af[4], bfr[4];
        #pragma unroll
        for (int i = 0; i < 4; ++i) {
            af[i]  = *reinterpret_cast<const bf16x8*>(&As[(wr * 64 + i * 16 + l16) * BK + quad * 8]);
            bfr[i] = *reinterpret_cast<const bf16x8*>(&Bs[(wc * 64 + i * 16 + l16) * BK + quad * 8]);
        }
        #pragma unroll
        for (int i = 0; i < 4; ++i)
            #pragma unroll
            for (int j = 0; j < 4; ++j)
                acc[i][j] = __builtin_amdgcn_mfma_f32_16x16x32_bf16(af[i], bfr[j], acc[i][j], 0, 0, 0);
    }

    // epilogue: bias + scatter (which/h uniform within each 16-col group)
    #pragma unroll
    for (int j = 0; j < 4; ++j) {
        int n = n0 + wc * 64 + j * 16 + l16;
        float bv = bias[n];
        int which = n >> 10;
        int c = n & 1023;
        int h = c >> 6, d = c & 63;
        #pragma unroll
        for (int i = 0; i < 4; ++i) {
            #pragma unroll
            for (int r = 0; r < 4; ++r) {
                int m = m0 + wr * 64 + i * 16 + quad * 4 + r;
                int t = m >> 1, b = m & 1;
                int bh = b * NH + h;
                float v = acc[i][j][r] + bv;
                if (which == 0)      Q16[((size_t)bh * T_LEN + t) * HD + d] = f2bf(v * QSCALE);
                else if (which == 1) K16[((size_t)bh * T_LEN + t) * HD + d] = f2bf(v);
                else                 Vt16[((size_t)bh * HD + d) * T_LEN + t] = f2bf(v);
            }
        }
    }
}

// ---------------------------------------------------------------------------
// Kernel 2: flash attention, bf16 MFMA, S^T formulation, NO online max.
// v5: BK 64 -> 128 keys per staged tile. Half the barriers (2 x 16 iters),
//     32 MFMA + 32 exp2 per phase per wave (m233: fatter phases amortize the
//     stage+bar overhead). LDS 64 KB (2 blocks/CU at grid 512, unchanged).
//  - 8-wave blocks, 16 q-rows/wave, dbuf, counted vmcnt(4).
//  - P in registers (permlane), deferred denominator, XCD remap, setprio.
// ---------------------------------------------------------------------------
__global__ __launch_bounds__(512, 4) void flash_mfma_kernel(
    const unsigned short* __restrict__ Qb, const unsigned short* __restrict__ Kb,
    const unsigned short* __restrict__ Vt, unsigned short* __restrict__ AO,
    float* __restrict__ Rrow)
{
    __shared__ unsigned short Ks[2][128 * 64];   // [key][d], swizzled chunks, 16KB ea
    __shared__ unsigned short Vs[2][64 * 128];   // [d][key], swizzled chunks, 16KB ea
    const int tid = threadIdx.x;                 // 0..511
    const int lane = tid & 63, wave = tid >> 6;  // wave 0..7
    const int quad = lane >> 4, l16 = lane & 15;

    // grid (16 qt, 32 bh) = 512 blocks; bijective XCD remap: xcd owns 4 bh.
    const int lin = blockIdx.y * gridDim.x + blockIdx.x;
    const int xcd = lin & 7, slot = lin >> 3;       // slot 0..63
    const int bh = xcd * 4 + (slot >> 4);
    const int qt = slot & 15;
    const int q0 = qt * 128;
    const int b = bh >> 4, h = bh & 15;

    // Q frag: wave owns q rows q0 + wave*16 + l16 (B-operand col)
    const unsigned short* Qp =
        Qb + ((size_t)bh * T_LEN + q0 + wave * 16 + l16) * HD;
    bf16x8 qf0 = *reinterpret_cast<const bf16x8*>(Qp + quad * 8);
    bf16x8 qf1 = *reinterpret_cast<const bf16x8*>(Qp + 32 + quad * 8);

    f32x4 zero4 = {0.f, 0.f, 0.f, 0.f};
    f32x4 oacc[4] = {zero4, zero4, zero4, zero4};   // O^T: [d-tile][r], col q=l16
    float l_part = 0.f;                              // per-lane partial denominator

    const unsigned short* Kbase = Kb + (size_t)bh * T_LEN * HD;
    const unsigned short* Vbase = Vt + (size_t)bh * HD * T_LEN;

    // staging indices: K tile = 128 rows x 8 chunks (1024), V = 64 x 16 (1024);
    // 2 chunks each per thread per tile.
    const int ck0 = tid, ck1 = tid + 512;                 // K chunk ids
    const int kr0 = ck0 >> 3, kc0 = (ck0 & 7) ^ (kr0 & 7);
    const int kr1 = ck1 >> 3, kc1 = (ck1 & 7) ^ (kr1 & 7);
    const int vr0 = ck0 >> 4, vc0 = (ck0 & 15) ^ (vr0 & 7);
    const int vr1 = ck1 >> 4, vc1 = (ck1 & 15) ^ (vr1 & 7);

    auto stage = [&](int buf, int kt) {
        async16(&Kbase[(size_t)(kt + kr0) * HD + kc0 * 8], &Ks[buf][ck0 * 8]);
        async16(&Kbase[(size_t)(kt + kr1) * HD + kc1 * 8], &Ks[buf][ck1 * 8]);
        async16(&Vbase[(size_t)vr0 * T_LEN + kt + vc0 * 8], &Vs[buf][ck0 * 8]);
        async16(&Vbase[(size_t)vr1 * T_LEN + kt + vc1 * 8], &Vs[buf][ck1 * 8]);
    };

    stage(0, 0);   // prologue

    int cur = 0;
    for (int kt = 0; kt < T_LEN; kt += 128) {
        if (kt + 128 < T_LEN) {
            stage(cur ^ 1, kt + 128);
            // drain current tile's 4 loads; keep next tile's 4 in flight
            asm volatile("s_waitcnt vmcnt(4)" ::: "memory");
        } else {
            asm volatile("s_waitcnt vmcnt(0)" ::: "memory");
        }
        bar();   // all waves' current-tile loads landed

        const unsigned short* Kt = Ks[cur];
        const unsigned short* Vv = Vs[cur];

        // S^T = K Q^T over 128 keys, in two 4-kb halves (keeps sacc[4] live)
        unsigned dlo[8], dhi[8];   // dlo[kb]=keys kb*16+quad*4+{0,1}, dhi=+{2,3}
        #pragma unroll
        for (int half = 0; half < 2; ++half) {
            f32x4 sacc[4] = {zero4, zero4, zero4, zero4};
            __builtin_amdgcn_s_setprio(1);
            #pragma unroll
            for (int j = 0; j < 4; ++j) {
                int kb = half * 4 + j;
                bf16x8 kf0 = *reinterpret_cast<const bf16x8*>(swz(Kt, kb * 16 + l16, quad));
                sacc[j] = __builtin_amdgcn_mfma_f32_16x16x32_bf16(kf0, qf0, sacc[j], 0, 0, 0);
                bf16x8 kf1 = *reinterpret_cast<const bf16x8*>(swz(Kt, kb * 16 + l16, 4 + quad));
                sacc[j] = __builtin_amdgcn_mfma_f32_16x16x32_bf16(kf1, qf1, sacc[j], 0, 0, 0);
            }
            __builtin_amdgcn_s_setprio(0);
            #pragma unroll
            for (int j = 0; j < 4; ++j) {
                float p0 = fexp2(sacc[j][0]);
                float p1 = fexp2(sacc[j][1]);
                float p2 = fexp2(sacc[j][2]);
                float p3 = fexp2(sacc[j][3]);
                l_part += (p0 + p1) + (p2 + p3);
                dlo[half * 4 + j] = pack2bf(p0, p1);
                dhi[half * 4 + j] = pack2bf(p2, p3);
            }
        }

        // redistribute P^T into PV B-operand frags (keys ks*32+quad*8+0..7)
        // and accumulate O^T += V^T P^T
        __builtin_amdgcn_s_setprio(1);
        #pragma unroll
        for (int ks = 0; ks < 4; ++ks) {
            unsigned w0, w1, w2, w3;
            xchg(dlo[2 * ks], dlo[2 * ks + 1], w0, w2);
            xchg(dhi[2 * ks], dhi[2 * ks + 1], w1, w3);
            union { bf16x8 v; unsigned u[4]; } P;
            P.u[0] = w0; P.u[1] = w1; P.u[2] = w2; P.u[3] = w3;
            #pragma unroll
            for (int dt = 0; dt < 4; ++dt) {
                bf16x8 va = *reinterpret_cast<const bf16x8*>(swz16(Vv, dt * 16 + l16, ks * 4 + quad));
                oacc[dt] = __builtin_amdgcn_mfma_f32_16x16x32_bf16(va, P.v, oacc[dt], 0, 0, 0);
            }
        }
        __builtin_amdgcn_s_setprio(0);

        bar();   // all waves done reading buffer `cur` before reuse
        cur ^= 1;
    }

    // epilogue: deferred denominator reduction (all 4 quads end up equal)
    l_part += __shfl_xor(l_part, 16);
    l_part += __shfl_xor(l_part, 32);
    float rl = 1.0f / l_part;
    int q = q0 + wave * 16 + l16;
    size_t base = ((size_t)q * BSZ + b) * EMB + h * HD;
    #pragma unroll
    for (int dt = 0; dt < 4; ++dt) {
        unsigned o[2] = { pack2bf(oacc[dt][0] * rl, oacc[dt][1] * rl),
                          pack2bf(oacc[dt][2] * rl, oacc[dt][3] * rl) };
        *reinterpret_cast<uint2*>(&AO[base + dt * 16 + quad * 4]) = *reinterpret_cast<uint2*>(o);
    }
    if (quad == 0)
        Rrow[(size_t)bh * T_LEN + q] = rl;   // reciprocal for avg kernel
}

// ---------------------------------------------------------------------------
// Kernel 3: averaged attention weights, bf16 MFMA, no max (exp2 units).
// v2: 8-wave 512-thread blocks, 128q x 128k output tile. Grid (16,16,2)=512
//     = 2 blocks/CU x 8 waves. Pair-head double-buffer staging (64 KB LDS),
//     counted vmcnt(4). Half the total barriers and half the Q re-reads of
//     the previous 1024-block version. Division-free (Rrow reciprocal).
// ---------------------------------------------------------------------------
__global__ __launch_bounds__(512, 4) void avg_mfma_kernel(
    const unsigned short* __restrict__ Qb, const unsigned short* __restrict__ Kb,
    const float* __restrict__ Rrow, float* __restrict__ avg_out)
{
    __shared__ unsigned short Ks[2][2][128 * 64];   // [buf][head-in-pair], 64 KB
    const int tid = threadIdx.x;                    // 0..511
    const int lane = tid & 63, wave = tid >> 6;
    const int quad = lane >> 4, l16 = lane & 15;
    const int kt = blockIdx.x, qt = blockIdx.y, b = blockIdx.z;
    const int q0 = qt * 128, k0 = kt * 128;

    // stage a pair of heads (2 x 1024 chunks = 4 chunks/thread) into Ks[buf]
    auto stage_pair = [&](int buf, int h0) {
        const unsigned short* Kg = Kb + ((size_t)(b * NH + h0) * T_LEN + k0) * HD;
        #pragma unroll
        for (int t = 0; t < 4; ++t) {
            int c = t * 512 + tid;           // 0..2047; c>>10 selects head
            int hh = c >> 10, cl = c & 1023;
            int r = cl >> 3, cc = (cl & 7) ^ (r & 7);
            async16(&Kg[(size_t)hh * T_LEN * HD + (size_t)r * HD + cc * 8],
                    &Ks[buf][0][0] + (size_t)c * 8);
        }
    };

    f32x4 zero4 = {0.f, 0.f, 0.f, 0.f};
    f32x4 acc[8];   // [kb], rows q = wave*16+quad*4+r, col k = kb*16+l16
    #pragma unroll
    for (int kb = 0; kb < 8; ++kb) acc[kb] = zero4;

    stage_pair(0, 0);
    int cur = 0;
    for (int g = 0; g < NH / 2; ++g) {
        if (g + 1 < NH / 2) {
            stage_pair(cur ^ 1, 2 * (g + 1));
            // newest 4 = next pair's stage loads; drains current pair's stage
            asm volatile("s_waitcnt vmcnt(4)" ::: "memory");
        } else {
            asm volatile("s_waitcnt vmcnt(0)" ::: "memory");
        }
        bar();

        #pragma unroll
        for (int hh = 0; hh < 2; ++hh) {
            const int bh = b * NH + 2 * g + hh;
            const unsigned short* Kt = Ks[cur][hh];
            const int qrow = q0 + wave * 16;
            const unsigned short* Qp = Qb + ((size_t)bh * T_LEN + qrow + l16) * HD;
            bf16x8 qf0 = *reinterpret_cast<const bf16x8*>(Qp + quad * 8);
            bf16x8 qf1 = *reinterpret_cast<const bf16x8*>(Qp + 32 + quad * 8);
            float4 rlv = *reinterpret_cast<const float4*>(
                &Rrow[(size_t)bh * T_LEN + qrow + quad * 4]);

            // S tile: lane holds rows q = qrow+quad*4+r, col key = kb*16+l16
            f32x4 sacc[8];
            __builtin_amdgcn_s_setprio(1);
            #pragma unroll
            for (int kb = 0; kb < 8; ++kb) {
                sacc[kb] = zero4;
                bf16x8 kf0 = *reinterpret_cast<const bf16x8*>(swz(Kt, kb * 16 + l16, quad));
                sacc[kb] = __builtin_amdgcn_mfma_f32_16x16x32_bf16(qf0, kf0, sacc[kb], 0, 0, 0);
                bf16x8 kf1 = *reinterpret_cast<const bf16x8*>(swz(Kt, kb * 16 + l16, 4 + quad));
                sacc[kb] = __builtin_amdgcn_mfma_f32_16x16x32_bf16(qf1, kf1, sacc[kb], 0, 0, 0);
            }
            __builtin_amdgcn_s_setprio(0);

            float rl4[4] = { rlv.x, rlv.y, rlv.z, rlv.w };
            #pragma unroll
            for (int kb = 0; kb < 8; ++kb)
                #pragma unroll
                for (int r = 0; r < 4; ++r)
                    acc[kb][r] += fexp2(sacc[kb][r]) * rl4[r];
        }
        bar();
        cur ^= 1;
    }

    #pragma unroll
    for (int r = 0; r < 4; ++r) {
        int q = q0 + wave * 16 + quad * 4 + r;
        size_t base = ((size_t)b * T_LEN + q) * T_LEN + k0;
        #pragma unroll
        for (int kb = 0; kb < 8; ++kb)
            avg_out[base + kb * 16 + l16] = acc[kb][r] * (1.0f / 16.0f);
    }
}

// ---------------------------------------------------------------------------
// Kernel 4: output projection, bf16 MFMA. out = AO @ out_w^T + out_b (fp32 out)
// ---------------------------------------------------------------------------
__global__ __launch_bounds__(256) void out_mfma_kernel(
    const unsigned short* __restrict__ A, const unsigned short* __restrict__ B,
    const float* __restrict__ bias, float* __restrict__ out)
{
    constexpr int BM = 128, BN = 128, BK = 32, K = 1024;
    __shared__ unsigned short As[BM * BK];
    __shared__ unsigned short Bs[BN * BK];
    const int tid = threadIdx.x;
    const int lane = tid & 63, wave = tid >> 6;
    const int quad = lane >> 4, l16 = lane & 15;
    const int wr = wave >> 1, wc = wave & 1;
    const int m0 = blockIdx.x * BM, n0 = blockIdx.y * BN;

    f32x4 zero4 = {0.f, 0.f, 0.f, 0.f};
    f32x4 acc[4][4];
    #pragma unroll
    for (int i = 0; i < 4; ++i)
        #pragma unroll
        for (int j = 0; j < 4; ++j) acc[i][j] = zero4;

    for (int k0 = 0; k0 < K; k0 += BK) {
        __syncthreads();
        #pragma unroll
        for (int t = 0; t < 2; ++t) {
            int c = t * 256 + tid;
            int m = c >> 2, kb = c & 3;
            async16(&A[(size_t)(m0 + m) * K + k0 + kb * 8], &As[c * 8]);
            async16(&B[(size_t)(n0 + m) * K + k0 + kb * 8], &Bs[c * 8]);
        }
        __syncthreads();
        bf16x8 af[4], bfr[4];
        #pragma unroll
        for (int i = 0; i < 4; ++i) {
            af[i]  = *reinterpret_cast<const bf16x8*>(&As[(wr * 64 + i * 16 + l16) * BK + quad * 8]);
            bfr[i] = *reinterpret_cast<const bf16x8*>(&Bs[(wc * 64 + i * 16 + l16) * BK + quad * 8]);
        }
        #pragma unroll
        for (int i = 0; i < 4; ++i)
            #pragma unroll
            for (int j = 0; j < 4; ++j)
                acc[i][j] = __builtin_amdgcn_mfma_f32_16x16x32_bf16(af[i], bfr[j], acc[i][j], 0, 0, 0);
    }

    #pragma unroll
    for (int j = 0; j < 4; ++j) {
        int n = n0 + wc * 64 + j * 16 + l16;
        float bv = bias[n];
        #pragma unroll
        for (int i = 0; i < 4; ++i) {
            #pragma unroll
            for (int r = 0; r < 4; ++r) {
                int m = m0 + wr * 64 + i * 16 + quad * 4 + r;
                out[(size_t)m * 1024 + n] = acc[i][j][r] + bv;
            }
        }
    }
}

// ---------------------------------------------------------------------------
extern "C" void kernel_launch(void* const* d_in, const int* in_sizes, int n_in,
                              void* d_out, int out_size, void* d_ws, size_t ws_size,
                              hipStream_t stream)
{
    const float* query = (const float*)d_in[0];   // [2048][2][1024]
    const float* wqkv  = (const float*)d_in[1];   // [3072][1024]
    const float* bqkv  = (const float*)d_in[2];   // [3072]
    const float* wout  = (const float*)d_in[3];   // [1024][1024]
    const float* bout  = (const float*)d_in[4];   // [1024]
    float* out = (float*)d_out;                   // [4096*1024] attn ++ [2*2048*2048] avg

    char* ws = (char*)d_ws;
    const size_t E_Q   = (size_t)M1 * EMB;        // 4M
    const size_t E_W   = (size_t)3 * EMB * EMB;   // 3M
    const size_t E_WO  = (size_t)EMB * EMB;       // 1M
    const size_t E_QKV = (size_t)BHN * T_LEN * HD;// 4M

    unsigned short* queryb = (unsigned short*)ws;                 // 8 MB
    unsigned short* wqkvb  = queryb + E_Q;                        // 6 MB
    unsigned short* woutb  = wqkvb + E_W;                         // 2 MB
    unsigned short* Q16    = woutb + E_WO;                        // 8 MB
    unsigned short* K16    = Q16 + E_QKV;                         // 8 MB
    unsigned short* Vt16   = K16 + E_QKV;                         // 8 MB
    unsigned short* AO16   = Vt16 + E_QKV;                        // 8 MB
    float* Lr = (float*)(AO16 + E_Q);
    const size_t need = (E_Q + E_W + E_WO + 4 * E_QKV) * 2 + (size_t)BHN * T_LEN * 4;
    if (ws_size < need) return;

    // one fused convert launch (dst regions are contiguous in ws)
    cvt3_kernel<<<(int)((E_Q + E_W + E_WO) / 8 / 256), 256, 0, stream>>>(
        query, wqkv, wout, queryb, (int)(E_Q / 8), (int)(E_W / 8));

    qkv_mfma_kernel<<<dim3(M1 / 128, 3072 / 128), 256, 0, stream>>>(queryb, wqkvb, bqkv, Q16, K16, Vt16);
    flash_mfma_kernel<<<dim3(T_LEN / 128, BHN), 512, 0, stream>>>(Q16, K16, Vt16, AO16, Lr);
    avg_mfma_kernel<<<dim3(T_LEN / 128, T_LEN / 128, BSZ), 512, 0, stream>>>(Q16, K16, Lr, out + (size_t)M1 * EMB);
    out_mfma_kernel<<<dim3(M1 / 128, 1024 / 128), 256, 0, stream>>>(AO16, woutb, bout, out);
}

// Round 6
// 238.155 us; speedup vs baseline: 1.1057x; 1.1057x over previous
//
#include <hip/hip_runtime.h>
#include <hip/hip_bf16.h>
#include <math.h>

// Problem constants
#define T_LEN 2048
#define BSZ   2
#define EMB   1024
#define NH    16
#define HD    64
#define BHN   (BSZ*NH)      // 32
#define M1    (T_LEN*BSZ)   // 4096 rows of the projection GEMMs
#define SCAL  0.125f        // HD^-0.5
#define QSCALE (0.125f * 1.44269504088896f)   // SCAL * log2(e): softmax uses exp2

typedef __attribute__((ext_vector_type(8))) short bf16x8;   // 8 bf16 = 4 VGPRs
typedef __attribute__((ext_vector_type(4))) float f32x4;
typedef __attribute__((ext_vector_type(2))) unsigned int u32x2;

__device__ inline unsigned short f2bf(float x) {
    union { float f; unsigned u; } v; v.f = x;
    unsigned r = v.u + 0x7FFF + ((v.u >> 16) & 1);   // RNE
    return (unsigned short)(r >> 16);
}

// packed f32x2 -> bf16x2 (v_cvt_pk_bf16_f32 on gfx950 via hip_bf16.h)
__device__ inline unsigned pack2bf(float a, float b) {
    union { __hip_bfloat162 h; unsigned u; } v;
    v.h = __float22bfloat162_rn(make_float2(a, b));
    return v.u;
}

__device__ inline float fexp2(float x) {
#if __has_builtin(__builtin_amdgcn_exp2f)
    return __builtin_amdgcn_exp2f(x);
#else
    return exp2f(x);
#endif
}

// async global->LDS, 16B per lane (wave-uniform LDS base + lane*16)
__device__ inline void async16(const unsigned short* g, unsigned short* l) {
    __builtin_amdgcn_global_load_lds(
        (const __attribute__((address_space(1))) void*)g,
        (__attribute__((address_space(3))) void*)l, 16, 0, 0);
}

// light barrier: IR-level memory fence + raw s_barrier. No vmcnt(0) drain
// (counted vmcnt handles staging), no sched_barrier(0) order-pinning (m141).
__device__ inline void bar() {
    asm volatile("" ::: "memory");
    __builtin_amdgcn_s_barrier();
    asm volatile("" ::: "memory");
}

// XOR-swizzled LDS address, 8 chunks (16B) per row: slot = c ^ (r&7).
__device__ inline const unsigned short* swz(const unsigned short* base, int r, int c) {
    return base + (((r << 3) + (c ^ (r & 7))) << 3);
}
// 16 chunks per row variant (row stride 256B); XOR on low 3 bits only.
__device__ inline const unsigned short* swz16(const unsigned short* base, int r, int c) {
    return base + (((r << 4) + (c ^ (r & 7))) << 3);
}

// In-register redistribution of the S^T (K*Q^T) output layout into the PV
// B-operand layout. Pure lane permutation among {l16, l16+16, l16+32, l16+48}.
__device__ inline void xchg(unsigned e, unsigned o, unsigned& w_lo, unsigned& w_hi) {
#if __has_builtin(__builtin_amdgcn_permlane32_swap) && __has_builtin(__builtin_amdgcn_permlane16_swap)
    u32x2 x = __builtin_amdgcn_permlane32_swap(e, o, false, false);
    u32x2 y = __builtin_amdgcn_permlane16_swap(x[0], x[1], false, false);
    w_lo = y[0]; w_hi = y[1];
#else
    int lane = (int)(threadIdx.x & 63);
    int quad = lane >> 4, l16 = lane & 15;
    int srcA = ((quad & 1) * 2) * 16 + l16;
    int srcB = ((quad & 1) * 2 + 1) * 16 + l16;
    unsigned ea = (unsigned)__shfl((int)e, srcA, 64);
    unsigned oa = (unsigned)__shfl((int)o, srcA, 64);
    unsigned eb = (unsigned)__shfl((int)e, srcB, 64);
    unsigned ob = (unsigned)__shfl((int)o, srcB, 64);
    w_lo = (quad >> 1) ? oa : ea;
    w_hi = (quad >> 1) ? ob : eb;
#endif
}

// ---------------------------------------------------------------------------
// Kernel 0: fused fp32 -> bf16 convert of all three inputs.
// ---------------------------------------------------------------------------
__global__ __launch_bounds__(256) void cvt3_kernel(
    const float* __restrict__ s0, const float* __restrict__ s1,
    const float* __restrict__ s2, unsigned short* __restrict__ dst,
    int n0, int n1)
{
    int idx = blockIdx.x * 256 + threadIdx.x;
    const float* src; int o;
    if (idx < n0)           { src = s0; o = idx; }
    else if (idx < n0 + n1) { src = s1; o = idx - n0; }
    else                    { src = s2; o = idx - n0 - n1; }
    float4 a = reinterpret_cast<const float4*>(src)[(size_t)o * 2];
    float4 c = reinterpret_cast<const float4*>(src)[(size_t)o * 2 + 1];
    unsigned w[4] = { pack2bf(a.x, a.y), pack2bf(a.z, a.w),
                      pack2bf(c.x, c.y), pack2bf(c.z, c.w) };
    reinterpret_cast<uint4*>(dst)[idx] = *reinterpret_cast<uint4*>(w);
}

// ---------------------------------------------------------------------------
// Kernel 1: QKV projection, bf16 MFMA (m97 structure).
// Q16 is pre-scaled by SCAL*log2(e) so attention softmax can use raw exp2.
// ---------------------------------------------------------------------------
__global__ __launch_bounds__(256) void qkv_mfma_kernel(
    const unsigned short* __restrict__ A, const unsigned short* __restrict__ B,
    const float* __restrict__ bias,
    unsigned short* __restrict__ Q16, unsigned short* __restrict__ K16,
    unsigned short* __restrict__ Vt16)
{
    constexpr int BM = 128, BN = 128, BK = 32, K = 1024;
    __shared__ unsigned short As[BM * BK];   // contiguous, no pad (global_load_lds)
    __shared__ unsigned short Bs[BN * BK];
    const int tid = threadIdx.x;
    const int lane = tid & 63, wave = tid >> 6;
    const int quad = lane >> 4, l16 = lane & 15;
    const int wr = wave >> 1, wc = wave & 1;
    const int m0 = blockIdx.x * BM, n0 = blockIdx.y * BN;

    f32x4 zero4 = {0.f, 0.f, 0.f, 0.f};
    f32x4 acc[4][4];
    #pragma unroll
    for (int i = 0; i < 4; ++i)
        #pragma unroll
        for (int j = 0; j < 4; ++j) acc[i][j] = zero4;

    for (int k0 = 0; k0 < K; k0 += BK) {
        __syncthreads();
        #pragma unroll
        for (int t = 0; t < 2; ++t) {
            int c = t * 256 + tid;           // 16B chunk id, 0..511
            int m = c >> 2, kb = c & 3;
            async16(&A[(size_t)(m0 + m) * K + k0 + kb * 8], &As[c * 8]);
            async16(&B[(size_t)(n0 + m) * K + k0 + kb * 8], &Bs[c * 8]);
        }
        __syncthreads();
        bf16x8 af[4], bfr[4];
        #pragma unroll
        for (int i = 0; i < 4; ++i) {
            af[i]  = *reinterpret_cast<const bf16x8*>(&As[(wr * 64 + i * 16 + l16) * BK + quad * 8]);
            bfr[i] = *reinterpret_cast<const bf16x8*>(&Bs[(wc * 64 + i * 16 + l16) * BK + quad * 8]);
        }
        #pragma unroll
        for (int i = 0; i < 4; ++i)
            #pragma unroll
            for (int j = 0; j < 4; ++j)
                acc[i][j] = __builtin_amdgcn_mfma_f32_16x16x32_bf16(af[i], bfr[j], acc[i][j], 0, 0, 0);
    }

    // epilogue: bias + scatter (which/h uniform within each 16-col group)
    #pragma unroll
    for (int j = 0; j < 4; ++j) {
        int n = n0 + wc * 64 + j * 16 + l16;
        float bv = bias[n];
        int which = n >> 10;
        int c = n & 1023;
        int h = c >> 6, d = c & 63;
        #pragma unroll
        for (int i = 0; i < 4; ++i) {
            #pragma unroll
            for (int r = 0; r < 4; ++r) {
                int m = m0 + wr * 64 + i * 16 + quad * 4 + r;
                int t = m >> 1, b = m & 1;
                int bh = b * NH + h;
                float v = acc[i][j][r] + bv;
                if (which == 0)      Q16[((size_t)bh * T_LEN + t) * HD + d] = f2bf(v * QSCALE);
                else if (which == 1) K16[((size_t)bh * T_LEN + t) * HD + d] = f2bf(v);
                else                 Vt16[((size_t)bh * HD + d) * T_LEN + t] = f2bf(v);
            }
        }
    }
}

// ---------------------------------------------------------------------------
// Kernel 2: flash attention, bf16 MFMA, S^T formulation, NO online max.
// v5 (kept from round 5 for attribution): BK=128 keys per staged tile,
// half the barriers, 32 MFMA + 32 exp2 per phase. LDS 64 KB, 2 blocks/CU.
// 8-wave blocks, dbuf, counted vmcnt(4), P in registers, XCD remap, setprio.
// ---------------------------------------------------------------------------
__global__ __launch_bounds__(512, 4) void flash_mfma_kernel(
    const unsigned short* __restrict__ Qb, const unsigned short* __restrict__ Kb,
    const unsigned short* __restrict__ Vt, unsigned short* __restrict__ AO,
    float* __restrict__ Rrow)
{
    __shared__ unsigned short Ks[2][128 * 64];   // [key][d], swizzled chunks, 16KB ea
    __shared__ unsigned short Vs[2][64 * 128];   // [d][key], swizzled chunks, 16KB ea
    const int tid = threadIdx.x;                 // 0..511
    const int lane = tid & 63, wave = tid >> 6;  // wave 0..7
    const int quad = lane >> 4, l16 = lane & 15;

    // grid (16 qt, 32 bh) = 512 blocks; bijective XCD remap: xcd owns 4 bh.
    const int lin = blockIdx.y * gridDim.x + blockIdx.x;
    const int xcd = lin & 7, slot = lin >> 3;       // slot 0..63
    const int bh = xcd * 4 + (slot >> 4);
    const int qt = slot & 15;
    const int q0 = qt * 128;
    const int b = bh >> 4, h = bh & 15;

    // Q frag: wave owns q rows q0 + wave*16 + l16 (B-operand col)
    const unsigned short* Qp =
        Qb + ((size_t)bh * T_LEN + q0 + wave * 16 + l16) * HD;
    bf16x8 qf0 = *reinterpret_cast<const bf16x8*>(Qp + quad * 8);
    bf16x8 qf1 = *reinterpret_cast<const bf16x8*>(Qp + 32 + quad * 8);

    f32x4 zero4 = {0.f, 0.f, 0.f, 0.f};
    f32x4 oacc[4] = {zero4, zero4, zero4, zero4};   // O^T: [d-tile][r], col q=l16
    float l_part = 0.f;                              // per-lane partial denominator

    const unsigned short* Kbase = Kb + (size_t)bh * T_LEN * HD;
    const unsigned short* Vbase = Vt + (size_t)bh * HD * T_LEN;

    // staging indices: K tile = 128 rows x 8 chunks (1024), V = 64 x 16 (1024);
    // 2 chunks each per thread per tile.
    const int ck0 = tid, ck1 = tid + 512;                 // K chunk ids
    const int kr0 = ck0 >> 3, kc0 = (ck0 & 7) ^ (kr0 & 7);
    const int kr1 = ck1 >> 3, kc1 = (ck1 & 7) ^ (kr1 & 7);
    const int vr0 = ck0 >> 4, vc0 = (ck0 & 15) ^ (vr0 & 7);
    const int vr1 = ck1 >> 4, vc1 = (ck1 & 15) ^ (vr1 & 7);

    auto stage = [&](int buf, int kt) {
        async16(&Kbase[(size_t)(kt + kr0) * HD + kc0 * 8], &Ks[buf][ck0 * 8]);
        async16(&Kbase[(size_t)(kt + kr1) * HD + kc1 * 8], &Ks[buf][ck1 * 8]);
        async16(&Vbase[(size_t)vr0 * T_LEN + kt + vc0 * 8], &Vs[buf][ck0 * 8]);
        async16(&Vbase[(size_t)vr1 * T_LEN + kt + vc1 * 8], &Vs[buf][ck1 * 8]);
    };

    stage(0, 0);   // prologue

    int cur = 0;
    for (int kt = 0; kt < T_LEN; kt += 128) {
        if (kt + 128 < T_LEN) {
            stage(cur ^ 1, kt + 128);
            // drain current tile's 4 loads; keep next tile's 4 in flight
            asm volatile("s_waitcnt vmcnt(4)" ::: "memory");
        } else {
            asm volatile("s_waitcnt vmcnt(0)" ::: "memory");
        }
        bar();   // all waves' current-tile loads landed

        const unsigned short* Kt = Ks[cur];
        const unsigned short* Vv = Vs[cur];

        // S^T = K Q^T over 128 keys, in two 4-kb halves (keeps sacc[4] live)
        unsigned dlo[8], dhi[8];   // dlo[kb]=keys kb*16+quad*4+{0,1}, dhi=+{2,3}
        #pragma unroll
        for (int half = 0; half < 2; ++half) {
            f32x4 sacc[4] = {zero4, zero4, zero4, zero4};
            __builtin_amdgcn_s_setprio(1);
            #pragma unroll
            for (int j = 0; j < 4; ++j) {
                int kb = half * 4 + j;
                bf16x8 kf0 = *reinterpret_cast<const bf16x8*>(swz(Kt, kb * 16 + l16, quad));
                sacc[j] = __builtin_amdgcn_mfma_f32_16x16x32_bf16(kf0, qf0, sacc[j], 0, 0, 0);
                bf16x8 kf1 = *reinterpret_cast<const bf16x8*>(swz(Kt, kb * 16 + l16, 4 + quad));
                sacc[j] = __builtin_amdgcn_mfma_f32_16x16x32_bf16(kf1, qf1, sacc[j], 0, 0, 0);
            }
            __builtin_amdgcn_s_setprio(0);
            #pragma unroll
            for (int j = 0; j < 4; ++j) {
                float p0 = fexp2(sacc[j][0]);
                float p1 = fexp2(sacc[j][1]);
                float p2 = fexp2(sacc[j][2]);
                float p3 = fexp2(sacc[j][3]);
                l_part += (p0 + p1) + (p2 + p3);
                dlo[half * 4 + j] = pack2bf(p0, p1);
                dhi[half * 4 + j] = pack2bf(p2, p3);
            }
        }

        // redistribute P^T into PV B-operand frags (keys ks*32+quad*8+0..7)
        // and accumulate O^T += V^T P^T
        __builtin_amdgcn_s_setprio(1);
        #pragma unroll
        for (int ks = 0; ks < 4; ++ks) {
            unsigned w0, w1, w2, w3;
            xchg(dlo[2 * ks], dlo[2 * ks + 1], w0, w2);
            xchg(dhi[2 * ks], dhi[2 * ks + 1], w1, w3);
            union { bf16x8 v; unsigned u[4]; } P;
            P.u[0] = w0; P.u[1] = w1; P.u[2] = w2; P.u[3] = w3;
            #pragma unroll
            for (int dt = 0; dt < 4; ++dt) {
                bf16x8 va = *reinterpret_cast<const bf16x8*>(swz16(Vv, dt * 16 + l16, ks * 4 + quad));
                oacc[dt] = __builtin_amdgcn_mfma_f32_16x16x32_bf16(va, P.v, oacc[dt], 0, 0, 0);
            }
        }
        __builtin_amdgcn_s_setprio(0);

        bar();   // all waves done reading buffer `cur` before reuse
        cur ^= 1;
    }

    // epilogue: deferred denominator reduction (all 4 quads end up equal)
    l_part += __shfl_xor(l_part, 16);
    l_part += __shfl_xor(l_part, 32);
    float rl = 1.0f / l_part;
    int q = q0 + wave * 16 + l16;
    size_t base = ((size_t)q * BSZ + b) * EMB + h * HD;
    #pragma unroll
    for (int dt = 0; dt < 4; ++dt) {
        unsigned o[2] = { pack2bf(oacc[dt][0] * rl, oacc[dt][1] * rl),
                          pack2bf(oacc[dt][2] * rl, oacc[dt][3] * rl) };
        *reinterpret_cast<uint2*>(&AO[base + dt * 16 + quad * 4]) = *reinterpret_cast<uint2*>(o);
    }
    if (quad == 0)
        Rrow[(size_t)bh * T_LEN + q] = rl;   // reciprocal for avg kernel
}

// ---------------------------------------------------------------------------
// Kernel 3: averaged attention weights, bf16 MFMA, no max (exp2 units).
// REVERTED to the round-4 known-good version: 256-thread blocks, 128q x 64k,
// pair-head dbuf staging (32 KB LDS), counted vmcnt(4), division-free, bar().
// Grid (32 kt, 16 qt, 2 b) = 1024 blocks. Round-5's 128k variant thrashed L2
// (FETCH 40->102 MB, WRITE 33->114 MB) -- this layout keeps K-tile sharers
// temporally adjacent and the per-stage footprint small (measured 39.7 MB).
// ---------------------------------------------------------------------------
__global__ __launch_bounds__(256) void avg_mfma_kernel(
    const unsigned short* __restrict__ Qb, const unsigned short* __restrict__ Kb,
    const float* __restrict__ Rrow, float* __restrict__ avg_out)
{
    __shared__ unsigned short Ks[2][2][64 * 64];   // [buf][head-in-pair], 32 KB
    const int tid = threadIdx.x;
    const int lane = tid & 63, wave = tid >> 6;
    const int quad = lane >> 4, l16 = lane & 15;
    const int kt = blockIdx.x, qt = blockIdx.y, b = blockIdx.z;
    const int q0 = qt * 128, k0 = kt * 64;

    // stage a pair of heads (2 x 512 chunks = 4 chunks/thread) into Ks[buf]
    auto stage_pair = [&](int buf, int h0) {
        const unsigned short* Kg = Kb + ((size_t)(b * NH + h0) * T_LEN + k0) * HD;
        #pragma unroll
        for (int t = 0; t < 4; ++t) {
            int c = t * 256 + tid;           // 0..1023; c>>9 selects head
            int hh = c >> 9, cl = c & 511;
            int r = cl >> 3, cc = (cl & 7) ^ (r & 7);
            async16(&Kg[(size_t)hh * T_LEN * HD + (size_t)r * HD + cc * 8],
                    &Ks[buf][0][0] + (size_t)c * 8);
        }
    };

    f32x4 zero4 = {0.f, 0.f, 0.f, 0.f};
    f32x4 acc[2][4];   // [strip][key-tile c], components r=0..3
    #pragma unroll
    for (int s = 0; s < 2; ++s)
        #pragma unroll
        for (int c = 0; c < 4; ++c) acc[s][c] = zero4;

    stage_pair(0, 0);
    int cur = 0;
    for (int g = 0; g < NH / 2; ++g) {
        if (g + 1 < NH / 2) {
            stage_pair(cur ^ 1, 2 * (g + 1));
            // newest 4 = next pair's stage loads; drains current pair's stage
            asm volatile("s_waitcnt vmcnt(4)" ::: "memory");
        } else {
            asm volatile("s_waitcnt vmcnt(0)" ::: "memory");
        }
        bar();

        #pragma unroll
        for (int hh = 0; hh < 2; ++hh) {
            const int bh = b * NH + 2 * g + hh;
            const unsigned short* Kt = Ks[cur][hh];
            // K fragments: shared by both q-strips (8 ds_read_b128)
            bf16x8 kf[4][2];
            #pragma unroll
            for (int c = 0; c < 4; ++c) {
                kf[c][0] = *reinterpret_cast<const bf16x8*>(swz(Kt, c * 16 + l16, quad));
                kf[c][1] = *reinterpret_cast<const bf16x8*>(swz(Kt, c * 16 + l16, 4 + quad));
            }
            #pragma unroll
            for (int s = 0; s < 2; ++s) {
                const int qrow = q0 + s * 64 + wave * 16;
                const unsigned short* Qp = Qb + ((size_t)bh * T_LEN + qrow + l16) * HD;
                bf16x8 qf0 = *reinterpret_cast<const bf16x8*>(Qp + quad * 8);
                bf16x8 qf1 = *reinterpret_cast<const bf16x8*>(Qp + 32 + quad * 8);
                float4 rlv = *reinterpret_cast<const float4*>(
                    &Rrow[(size_t)bh * T_LEN + qrow + quad * 4]);

                // S strip: lane holds rows q = qrow+quad*4+r, col key = c*16+l16
                f32x4 sacc[4] = {zero4, zero4, zero4, zero4};
                __builtin_amdgcn_s_setprio(1);
                #pragma unroll
                for (int c = 0; c < 4; ++c) {
                    sacc[c] = __builtin_amdgcn_mfma_f32_16x16x32_bf16(qf0, kf[c][0], sacc[c], 0, 0, 0);
                    sacc[c] = __builtin_amdgcn_mfma_f32_16x16x32_bf16(qf1, kf[c][1], sacc[c], 0, 0, 0);
                }
                __builtin_amdgcn_s_setprio(0);

                float rl4[4] = { rlv.x, rlv.y, rlv.z, rlv.w };
                #pragma unroll
                for (int c = 0; c < 4; ++c)
                    #pragma unroll
                    for (int r = 0; r < 4; ++r)
                        acc[s][c][r] += fexp2(sacc[c][r]) * rl4[r];
            }
        }
        bar();
        cur ^= 1;
    }

    #pragma unroll
    for (int s = 0; s < 2; ++s)
        #pragma unroll
        for (int r = 0; r < 4; ++r) {
            int q = q0 + s * 64 + wave * 16 + quad * 4 + r;
            size_t base = ((size_t)b * T_LEN + q) * T_LEN + k0;
            #pragma unroll
            for (int c = 0; c < 4; ++c)
                avg_out[base + c * 16 + l16] = acc[s][c][r] * (1.0f / 16.0f);
        }
}

// ---------------------------------------------------------------------------
// Kernel 4: output projection, bf16 MFMA. out = AO @ out_w^T + out_b (fp32 out)
// ---------------------------------------------------------------------------
__global__ __launch_bounds__(256) void out_mfma_kernel(
    const unsigned short* __restrict__ A, const unsigned short* __restrict__ B,
    const float* __restrict__ bias, float* __restrict__ out)
{
    constexpr int BM = 128, BN = 128, BK = 32, K = 1024;
    __shared__ unsigned short As[BM * BK];
    __shared__ unsigned short Bs[BN * BK];
    const int tid = threadIdx.x;
    const int lane = tid & 63, wave = tid >> 6;
    const int quad = lane >> 4, l16 = lane & 15;
    const int wr = wave >> 1, wc = wave & 1;
    const int m0 = blockIdx.x * BM, n0 = blockIdx.y * BN;

    f32x4 zero4 = {0.f, 0.f, 0.f, 0.f};
    f32x4 acc[4][4];
    #pragma unroll
    for (int i = 0; i < 4; ++i)
        #pragma unroll
        for (int j = 0; j < 4; ++j) acc[i][j] = zero4;

    for (int k0 = 0; k0 < K; k0 += BK) {
        __syncthreads();
        #pragma unroll
        for (int t = 0; t < 2; ++t) {
            int c = t * 256 + tid;
            int m = c >> 2, kb = c & 3;
            async16(&A[(size_t)(m0 + m) * K + k0 + kb * 8], &As[c * 8]);
            async16(&B[(size_t)(n0 + m) * K + k0 + kb * 8], &Bs[c * 8]);
        }
        __syncthreads();
        bf16x8 af[4], bfr[4];
        #pragma unroll
        for (int i = 0; i < 4; ++i) {
            af[i]  = *reinterpret_cast<const bf16x8*>(&As[(wr * 64 + i * 16 + l16) * BK + quad * 8]);
            bfr[i] = *reinterpret_cast<const bf16x8*>(&Bs[(wc * 64 + i * 16 + l16) * BK + quad * 8]);
        }
        #pragma unroll
        for (int i = 0; i < 4; ++i)
            #pragma unroll
            for (int j = 0; j < 4; ++j)
                acc[i][j] = __builtin_amdgcn_mfma_f32_16x16x32_bf16(af[i], bfr[j], acc[i][j], 0, 0, 0);
    }

    #pragma unroll
    for (int j = 0; j < 4; ++j) {
        int n = n0 + wc * 64 + j * 16 + l16;
        float bv = bias[n];
        #pragma unroll
        for (int i = 0; i < 4; ++i) {
            #pragma unroll
            for (int r = 0; r < 4; ++r) {
                int m = m0 + wr * 64 + i * 16 + quad * 4 + r;
                out[(size_t)m * 1024 + n] = acc[i][j][r] + bv;
            }
        }
    }
}

// ---------------------------------------------------------------------------
extern "C" void kernel_launch(void* const* d_in, const int* in_sizes, int n_in,
                              void* d_out, int out_size, void* d_ws, size_t ws_size,
                              hipStream_t stream)
{
    const float* query = (const float*)d_in[0];   // [2048][2][1024]
    const float* wqkv  = (const float*)d_in[1];   // [3072][1024]
    const float* bqkv  = (const float*)d_in[2];   // [3072]
    const float* wout  = (const float*)d_in[3];   // [1024][1024]
    const float* bout  = (const float*)d_in[4];   // [1024]
    float* out = (float*)d_out;                   // [4096*1024] attn ++ [2*2048*2048] avg

    char* ws = (char*)d_ws;
    const size_t E_Q   = (size_t)M1 * EMB;        // 4M
    const size_t E_W   = (size_t)3 * EMB * EMB;   // 3M
    const size_t E_WO  = (size_t)EMB * EMB;       // 1M
    const size_t E_QKV = (size_t)BHN * T_LEN * HD;// 4M

    unsigned short* queryb = (unsigned short*)ws;                 // 8 MB
    unsigned short* wqkvb  = queryb + E_Q;                        // 6 MB
    unsigned short* woutb  = wqkvb + E_W;                         // 2 MB
    unsigned short* Q16    = woutb + E_WO;                        // 8 MB
    unsigned short* K16    = Q16 + E_QKV;                         // 8 MB
    unsigned short* Vt16   = K16 + E_QKV;                         // 8 MB
    unsigned short* AO16   = Vt16 + E_QKV;                        // 8 MB
    float* Lr = (float*)(AO16 + E_Q);
    const size_t need = (E_Q + E_W + E_WO + 4 * E_QKV) * 2 + (size_t)BHN * T_LEN * 4;
    if (ws_size < need) return;

    // one fused convert launch (dst regions are contiguous in ws)
    cvt3_kernel<<<(int)((E_Q + E_W + E_WO) / 8 / 256), 256, 0, stream>>>(
        query, wqkv, wout, queryb, (int)(E_Q / 8), (int)(E_W / 8));

    qkv_mfma_kernel<<<dim3(M1 / 128, 3072 / 128), 256, 0, stream>>>(queryb, wqkvb, bqkv, Q16, K16, Vt16);
    flash_mfma_kernel<<<dim3(T_LEN / 128, BHN), 512, 0, stream>>>(Q16, K16, Vt16, AO16, Lr);
    avg_mfma_kernel<<<dim3(T_LEN / 64, T_LEN / 128, BSZ), 256, 0, stream>>>(Q16, K16, Lr, out + (size_t)M1 * EMB);
    out_mfma_kernel<<<dim3(M1 / 128, 1024 / 128), 256, 0, stream>>>(AO16, woutb, bout, out);
}